// Round 4
// baseline (2238.870 us; speedup 1.0000x reference)
//
#include <hip/hip_runtime.h>

// Problem constants
#define N_NODESC 50000
#define N_EDGESC 800000
#define EPSF 1e-5f
#define TILE_N 64
#define NTILE2 782                  // ceil(50000/64)
#define NKEY2  (NTILE2 * 16)        // 12512 (tile,combo) keys
#define NKPAD  12544                // 49*256
#define NKBLK  49
#define NEBLK  3125                 // 800000/256

// ---- ws layout (bytes) ----
#define WS_SCALE 0
#define WS_SHIFT 256
#define WS_BSUM  512
#define WS_PBUF  768                  // 782*128 f32 = 400384
#define WS_HIST  401408               // 12544 int
#define WS_FILL  451584               // 12544 int
#define WS_SEG   501760               // 12800 int
#define WS_ELIST 552960               // 800000 int (packed src|dloc<<16)
#define WS_HB    3752960              // 50000*64 f32
#define WS_OUTB  16552960             // 50000*64 f32

__device__ __forceinline__ int edge_key(int d, int c) {
    return (d >> 6) * 16 + c;
}

// ---------------- histogram over (tile,combo) ----------------
__global__ __launch_bounds__(256)
void k_hist(const int* __restrict__ src, const int* __restrict__ dst,
            const int* __restrict__ labels, const int* __restrict__ bidx,
            int* __restrict__ hist)
{
    const int e = blockIdx.x * 256 + threadIdx.x;
    if (e >= N_EDGESC) return;
    const int s = src[e], d = dst[e];
    const int c = (labels[d] * 2 + labels[s]) * 4 + bidx[e];
    atomicAdd(&hist[edge_key(d, c)], 1);
}

__global__ __launch_bounds__(256)
void k_bsum(const int* __restrict__ hist, int* __restrict__ bsum)
{
    __shared__ int s[256];
    const int i = blockIdx.x * 256 + threadIdx.x;
    s[threadIdx.x] = hist[i];
    __syncthreads();
    for (int off = 128; off > 0; off >>= 1) {
        if (threadIdx.x < off) s[threadIdx.x] += s[threadIdx.x + off];
        __syncthreads();
    }
    if (threadIdx.x == 0) bsum[blockIdx.x] = s[0];
}

__global__ void k_bscan(int* __restrict__ bsum)   // exclusive scan of NKBLK entries
{
    __shared__ int s[NKBLK];
    if (threadIdx.x < NKBLK) s[threadIdx.x] = bsum[threadIdx.x];
    __syncthreads();
    if (threadIdx.x == 0) {
        int run = 0;
        for (int i = 0; i < NKBLK; ++i) { const int v = s[i]; s[i] = run; run += v; }
    }
    __syncthreads();
    if (threadIdx.x < NKBLK) bsum[threadIdx.x] = s[threadIdx.x];
}

__global__ __launch_bounds__(256)
void k_escan(const int* __restrict__ hist, const int* __restrict__ bsum,
             int* __restrict__ seg)
{
    __shared__ int s[256];
    const int t = threadIdx.x;
    const int i = blockIdx.x * 256 + t;
    const int v = hist[i];
    s[t] = v; __syncthreads();
    for (int off = 1; off < 256; off <<= 1) {
        const int x = (t >= off) ? s[t - off] : 0;
        __syncthreads();
        s[t] += x;
        __syncthreads();
    }
    seg[i] = bsum[blockIdx.x] + s[t] - v;   // exclusive
}

// scatter packed (src | dloc<<16) into key-sorted order
__global__ __launch_bounds__(256)
void k_scat(const int* __restrict__ src, const int* __restrict__ dst,
            const int* __restrict__ labels, const int* __restrict__ bidx,
            const int* __restrict__ seg, int* __restrict__ fill,
            int* __restrict__ elist)
{
    const int e = blockIdx.x * 256 + threadIdx.x;
    if (e >= N_EDGESC) return;
    const int s = src[e], d = dst[e];
    const int c = (labels[d] * 2 + labels[s]) * 4 + bidx[e];
    const int k = edge_key(d, c);
    const int pos = seg[k] + atomicAdd(&fill[k], 1);
    elist[pos] = s | ((d & 63) << 16);
}

// ---------------- h = in @ W + b (layer 0) ----------------
__global__ __launch_bounds__(256)
void k_h(const float* __restrict__ in, const float* __restrict__ W,
         const float* __restrict__ b, float* __restrict__ h, const int F)
{
    const int t = blockIdx.x * 256 + threadIdx.x;
    if (t >= N_NODESC * 64) return;
    const int n = t >> 6, e = t & 63;
    const float* __restrict__ xr = in + (long)n * F;
    float acc = b[e];
    for (int f = 0; f < F; f += 4) {
        acc += xr[f]     * W[f * 64 + e];
        acc += xr[f + 1] * W[(f + 1) * 64 + e];
        acc += xr[f + 2] * W[(f + 2) * 64 + e];
        acc += xr[f + 3] * W[(f + 3) * 64 + e];
    }
    h[t] = acc;
}

// ---------------- fused LN-apply + relu + next-layer W GEMM ----------------
__global__ __launch_bounds__(256)
void k_happly(const float* __restrict__ outb, const float* __restrict__ scale,
              const float* __restrict__ shift, const float* __restrict__ W,
              const float* __restrict__ b, float* __restrict__ hB)
{
    __shared__ float act[4][64];
    const int nl = threadIdx.x >> 6, o = threadIdx.x & 63;
    const int n = blockIdx.x * 4 + nl;
    const float v = outb[(long)n * 64 + o] * scale[o] + shift[o];
    act[nl][o] = fmaxf(v, 0.f);
    __syncthreads();
    float a = b[o];
#pragma unroll 16
    for (int f = 0; f < 64; ++f) a += act[nl][f] * W[f * 64 + o];
    hB[(long)n * 64 + o] = a;
}

// ---------------- fused transform + aggregate (LDS accumulator) ----------------
// One block per 64-dst tile. Wave w owns combos {w, w+4, w+8, w+12}.
// Per 16-edge chunk: gather h rows -> hbuf, mini-GEMM vs M row (regs), ds-atomic
// accumulate into acc[dloc][feat]. Single barrier, then epilogue.
__global__ __launch_bounds__(256, 4)
void k_edge2(const float* __restrict__ h, const int* __restrict__ elist,
             const int* __restrict__ seg, const float* __restrict__ M,
             float* __restrict__ outb, float* __restrict__ pbuf)
{
    __shared__ float  acc[TILE_N][64];       // 16 KB
    __shared__ float4 hbuf[4][256];          // 16 KB
    __shared__ float  rsum[4][64], rsq[4][64];
    const int tid = threadIdx.x;
    const int w = tid >> 6, lane = tid & 63;
    const int jj = lane >> 2, q = lane & 3;
    const int tile = blockIdx.x;
    const float4* __restrict__ h4 = (const float4*)h;

#pragma unroll
    for (int i = 0; i < 16; ++i) ((float*)acc)[tid + 256 * i] = 0.f;
    __syncthreads();

#pragma unroll 1
    for (int ci = 0; ci < 4; ++ci) {
        const int c = w + 4 * ci;
        const float4* __restrict__ M4 = (const float4*)(M + c * 4096 + lane * 64);
        const int s0 = seg[tile * 16 + c];
        const int s1 = seg[tile * 16 + c + 1];

        for (int p = s0; p < s1; p += 16) {
            const int nv = min(16, s1 - p);
            int ep = 0;
            if (lane < nv) ep = elist[p + lane];
            const int  esel = __shfl(ep, jj);
            const bool jv = (jj < nv);
            const int  sj = esel & 0xFFFF;
#pragma unroll
            for (int r = 0; r < 4; ++r) {
                float4 v = make_float4(0.f, 0.f, 0.f, 0.f);
                if (jv) v = h4[sj * 16 + q + 4 * r];
                hbuf[w][(q + 4 * r) * 16 + jj] = v;
            }
            asm volatile("s_waitcnt lgkmcnt(0)" ::: "memory");

            float aj[16];
#pragma unroll
            for (int j = 0; j < 16; ++j) aj[j] = 0.f;

#pragma unroll 1
            for (int hf = 0; hf < 2; ++hf) {
                float4 mr[8];
#pragma unroll
                for (int r = 0; r < 8; ++r) mr[r] = M4[8 * hf + r];
#pragma unroll
                for (int f4h = 0; f4h < 8; ++f4h) {
                    const float4 m = mr[f4h];
                    const int f4 = 8 * hf + f4h;
#pragma unroll
                    for (int j = 0; j < 16; ++j) {
                        const float4 hv = hbuf[w][f4 * 16 + j];
                        aj[j] += m.x * hv.x + m.y * hv.y + m.z * hv.z + m.w * hv.w;
                    }
                }
            }
#pragma unroll
            for (int j = 0; j < 16; ++j) {
                if (j < nv) {
                    const int dl = __shfl(ep, j) >> 16;
                    atomicAdd(&acc[dl][lane], aj[j]);
                }
            }
        }
    }
    __syncthreads();

    // epilogue: residual + store + LN partials
    const int o = tid & 63;
    float s1v = 0.f, s2v = 0.f;
#pragma unroll
    for (int i = 0; i < 16; ++i) {
        const int idx = tid + 256 * i;
        const int d = idx >> 6;
        const int gd = tile * TILE_N + d;
        if (gd < N_NODESC) {
            const float v = acc[d][o] + h[(long)gd * 64 + o];
            outb[(long)gd * 64 + o] = v;
            s1v += v; s2v += v * v;
        }
    }
    rsum[tid >> 6][o] = s1v; rsq[tid >> 6][o] = s2v;
    __syncthreads();
    if (tid < 64) {
        float t1 = 0.f, t2 = 0.f;
#pragma unroll
        for (int k = 0; k < 4; ++k) { t1 += rsum[k][tid]; t2 += rsq[k][tid]; }
        pbuf[tile * 128 + tid] = t1;
        pbuf[tile * 128 + 64 + tid] = t2;
    }
}

// ---------------- reduce LN partials -> scale/shift ----------------
__global__ __launch_bounds__(1024)
void k_norm2(const float* __restrict__ pbuf, const float* __restrict__ g,
             const float* __restrict__ be, float* __restrict__ scale,
             float* __restrict__ shift)
{
    __shared__ float s[1024];
    const int t = threadIdx.x, j = t & 127, gg = t >> 7;
    float a = 0.f;
    for (int b = gg; b < NTILE2; b += 8) a += pbuf[b * 128 + j];
    s[t] = a;
    __syncthreads();
    if (t < 128) {
        float tot = 0.f;
#pragma unroll
        for (int k = 0; k < 8; ++k) tot += s[j + 128 * k];
        s[t] = tot;
    }
    __syncthreads();
    if (t < 64) {
        const double mu  = (double)s[t] / (double)N_NODESC;
        const double var = (double)s[64 + t] / (double)N_NODESC - mu * mu;
        const double sc  = (double)g[t] / sqrt(var + (double)EPSF);
        scale[t] = (float)sc;
        shift[t] = (float)((double)be[t] - mu * sc);
    }
}

// ---------------- final projection (LN apply fused) ----------------
__global__ __launch_bounds__(256)
void k_out(const float* __restrict__ outb, const float* __restrict__ scale,
           const float* __restrict__ shift, const float* __restrict__ resW,
           const float* __restrict__ resb, float* __restrict__ out)
{
    const int n = blockIdx.x * 256 + threadIdx.x;
    if (n >= N_NODESC) return;
    float a0 = resb[0], a1 = resb[1];
    const float* __restrict__ r = outb + (long)n * 64;
#pragma unroll 8
    for (int e = 0; e < 64; ++e) {
        const float v = fmaxf(r[e] * scale[e] + shift[e], 0.f);
        a0 += v * resW[2 * e];
        a1 += v * resW[2 * e + 1];
    }
    out[2 * n] = a0;
    out[2 * n + 1] = a1;
}

extern "C" void kernel_launch(void* const* d_in, const int* in_sizes, int n_in,
                              void* d_out, int out_size, void* d_ws, size_t ws_size,
                              hipStream_t stream)
{
    const float* x      = (const float*)d_in[0];
    const float* M      = (const float*)d_in[1];   // (16,64,64) row-major [c][o][k]
    const int*   src    = (const int*)d_in[2];
    const int*   dst    = (const int*)d_in[3];
    const int*   labels = (const int*)d_in[4];
    const int*   bidx   = (const int*)d_in[5];
    const float* resW   = (const float*)d_in[18];
    const float* resb   = (const float*)d_in[19];
    float* out = (float*)d_out;

    char* ws = (char*)d_ws;
    float* scale = (float*)(ws + WS_SCALE);
    float* shift = (float*)(ws + WS_SHIFT);
    int*   bsum  = (int*)(ws + WS_BSUM);
    float* pbuf  = (float*)(ws + WS_PBUF);
    int*   hist  = (int*)(ws + WS_HIST);
    int*   fill  = (int*)(ws + WS_FILL);
    int*   seg   = (int*)(ws + WS_SEG);
    int*   elist = (int*)(ws + WS_ELIST);
    float* hB    = (float*)(ws + WS_HB);
    float* outb  = (float*)(ws + WS_OUTB);

    const int NB64 = (N_NODESC * 64 + 255) / 256;  // 12500

    // ---- preprocessing (graph constant across layers) ----
    hipMemsetAsync(hist, 0, 2 * NKPAD * sizeof(int), stream);   // hist + fill
    k_hist<<<NEBLK, 256, 0, stream>>>(src, dst, labels, bidx, hist);
    k_bsum<<<NKBLK, 256, 0, stream>>>(hist, bsum);
    k_bscan<<<1, 64, 0, stream>>>(bsum);
    k_escan<<<NKBLK, 256, 0, stream>>>(hist, bsum, seg);
    k_scat<<<NEBLK, 256, 0, stream>>>(src, dst, labels, bidx, seg, fill, elist);

    for (int l = 0; l < 3; ++l) {
        const float* W  = (const float*)d_in[6 + 4 * l];
        const float* b  = (const float*)d_in[7 + 4 * l];
        const float* g  = (const float*)d_in[8 + 4 * l];
        const float* be = (const float*)d_in[9 + 4 * l];

        if (l == 0) {
            k_h<<<NB64, 256, 0, stream>>>(x, W, b, hB, 128);
        } else {
            k_happly<<<N_NODESC / 4, 256, 0, stream>>>(outb, scale, shift, W, b, hB);
        }
        k_edge2<<<NTILE2, 256, 0, stream>>>(hB, elist, seg, M, outb, pbuf);
        k_norm2<<<1, 1024, 0, stream>>>(pbuf, g, be, scale, shift);
    }
    k_out<<<(N_NODESC + 255) / 256, 256, 0, stream>>>(outb, scale, shift, resW, resb, out);
    (void)in_sizes; (void)n_in; (void)out_size; (void)ws_size;
}

// Round 5
// 1399.143 us; speedup vs baseline: 1.6002x; 1.6002x over previous
//
#include <hip/hip_runtime.h>

// Problem constants
#define N_NODESC 50000
#define N_EDGESC 800000
#define EPSF 1e-5f
#define TILE_N 64
#define NTILE2 782                  // ceil(50000/64)
#define NKPAD  12544                // 49*256 >= 782*16
#define NKBLK  49
#define NEBLK  3125                 // 800000/256

typedef __attribute__((ext_vector_type(8))) short short8;
typedef __attribute__((ext_vector_type(16))) float f32x16;

// ---- ws layout (bytes) ----
#define WS_SCALE 0
#define WS_SHIFT 256
#define WS_BSUM  512
#define WS_PBUF  768                  // 782*128 f32
#define WS_HIST  401408               // 12544 int
#define WS_FILL  451584               // 12544 int
#define WS_SEG   501760               // 12800 int
#define WS_ELIST 552960               // 800000 int (src | dloc<<16)
#define WS_AHI   3752960              // 16*2*4*64*8 ushort = 128 KB
#define WS_ALO   3884032
#define WS_HHI   4015104              // 50000*64 ushort
#define WS_HLO   10415104
#define WS_HB    16815104             // 50000*64 f32
#define WS_OUTB  29615104

__device__ __forceinline__ int edge_key(int d, int c) {
    return (d >> 6) * 16 + c;
}

// ---------------- preprocessing (identical structure to R4, which passed) ----
__global__ __launch_bounds__(256)
void k_hist(const int* __restrict__ src, const int* __restrict__ dst,
            const int* __restrict__ labels, const int* __restrict__ bidx,
            int* __restrict__ hist)
{
    const int e = blockIdx.x * 256 + threadIdx.x;
    if (e >= N_EDGESC) return;
    const int s = src[e], d = dst[e];
    const int c = (labels[d] * 2 + labels[s]) * 4 + bidx[e];
    atomicAdd(&hist[edge_key(d, c)], 1);
}

__global__ __launch_bounds__(256)
void k_bsum(const int* __restrict__ hist, int* __restrict__ bsum)
{
    __shared__ int s[256];
    const int i = blockIdx.x * 256 + threadIdx.x;
    s[threadIdx.x] = hist[i];
    __syncthreads();
    for (int off = 128; off > 0; off >>= 1) {
        if (threadIdx.x < off) s[threadIdx.x] += s[threadIdx.x + off];
        __syncthreads();
    }
    if (threadIdx.x == 0) bsum[blockIdx.x] = s[0];
}

__global__ void k_bscan(int* __restrict__ bsum)
{
    __shared__ int s[NKBLK];
    if (threadIdx.x < NKBLK) s[threadIdx.x] = bsum[threadIdx.x];
    __syncthreads();
    if (threadIdx.x == 0) {
        int run = 0;
        for (int i = 0; i < NKBLK; ++i) { const int v = s[i]; s[i] = run; run += v; }
    }
    __syncthreads();
    if (threadIdx.x < NKBLK) bsum[threadIdx.x] = s[threadIdx.x];
}

__global__ __launch_bounds__(256)
void k_escan(const int* __restrict__ hist, const int* __restrict__ bsum,
             int* __restrict__ seg)
{
    __shared__ int s[256];
    const int t = threadIdx.x;
    const int i = blockIdx.x * 256 + t;
    const int v = hist[i];
    s[t] = v; __syncthreads();
    for (int off = 1; off < 256; off <<= 1) {
        const int x = (t >= off) ? s[t - off] : 0;
        __syncthreads();
        s[t] += x;
        __syncthreads();
    }
    seg[i] = bsum[blockIdx.x] + s[t] - v;
}

__global__ __launch_bounds__(256)
void k_scat(const int* __restrict__ src, const int* __restrict__ dst,
            const int* __restrict__ labels, const int* __restrict__ bidx,
            const int* __restrict__ seg, int* __restrict__ fill,
            int* __restrict__ elist)
{
    const int e = blockIdx.x * 256 + threadIdx.x;
    if (e >= N_EDGESC) return;
    const int s = src[e], d = dst[e];
    const int c = (labels[d] * 2 + labels[s]) * 4 + bidx[e];
    const int k = edge_key(d, c);
    const int pos = seg[k] + atomicAdd(&fill[k], 1);
    elist[pos] = s | ((d & 63) << 16);
}

// ---- precompute MFMA A-fragments for the 16 matrices (split bf16 hi/lo) ----
// A element (c, tile t, kstep s, lane, j) = M[c][(lane&31)+32t][16s + 8*(lane>>5) + j]
__global__ void k_mfrag(const float* __restrict__ M, ushort* __restrict__ Ahi,
                        ushort* __restrict__ Alo)
{
    const int c = blockIdx.x;
    for (int slot = threadIdx.x; slot < 512; slot += 256) {
        const int t = slot >> 8, s = (slot >> 6) & 3, lane = slot & 63;
        const int row = (lane & 31) + 32 * t;
        const int kb = 16 * s + 8 * (lane >> 5);
        const int fid = ((c * 2 + t) * 4 + s) * 64 + lane;
#pragma unroll
        for (int j = 0; j < 8; ++j) {
            const float v = M[c * 4096 + row * 64 + kb + j];
            const unsigned b = __float_as_uint(v);
            const float lof = v - __uint_as_float(b & 0xFFFF0000u);
            Ahi[fid * 8 + j] = (ushort)(b >> 16);
            Alo[fid * 8 + j] = (ushort)(__float_as_uint(lof) >> 16);
        }
    }
}

// ---------------- h = in @ W + b, + split-bf16 outputs ----------------
__global__ __launch_bounds__(256)
void k_h(const float* __restrict__ in, const float* __restrict__ W,
         const float* __restrict__ b, float* __restrict__ h,
         ushort* __restrict__ hhi, ushort* __restrict__ hlo, const int F)
{
    const int t = blockIdx.x * 256 + threadIdx.x;
    if (t >= N_NODESC * 64) return;
    const int n = t >> 6, e = t & 63;
    const float* __restrict__ xr = in + (long)n * F;
    float acc = b[e];
    for (int f = 0; f < F; f += 4) {
        acc += xr[f]     * W[f * 64 + e];
        acc += xr[f + 1] * W[(f + 1) * 64 + e];
        acc += xr[f + 2] * W[(f + 2) * 64 + e];
        acc += xr[f + 3] * W[(f + 3) * 64 + e];
    }
    h[t] = acc;
    const unsigned bb = __float_as_uint(acc);
    const float lof = acc - __uint_as_float(bb & 0xFFFF0000u);
    hhi[t] = (ushort)(bb >> 16);
    hlo[t] = (ushort)(__float_as_uint(lof) >> 16);
}

// ---------------- fused LN-apply + relu + next-layer GEMM + split ----------------
__global__ __launch_bounds__(256)
void k_happly(const float* __restrict__ outb, const float* __restrict__ scale,
              const float* __restrict__ shift, const float* __restrict__ W,
              const float* __restrict__ b, float* __restrict__ h,
              ushort* __restrict__ hhi, ushort* __restrict__ hlo)
{
    __shared__ float act[4][64];
    const int nl = threadIdx.x >> 6, o = threadIdx.x & 63;
    const int n = blockIdx.x * 4 + nl;
    const float v = outb[(long)n * 64 + o] * scale[o] + shift[o];
    act[nl][o] = fmaxf(v, 0.f);
    __syncthreads();
    float a = b[o];
#pragma unroll 16
    for (int f = 0; f < 64; ++f) a += act[nl][f] * W[f * 64 + o];
    const long t = (long)n * 64 + o;
    h[t] = a;
    const unsigned bb = __float_as_uint(a);
    const float lof = a - __uint_as_float(bb & 0xFFFF0000u);
    hhi[t] = (ushort)(bb >> 16);
    hlo[t] = (ushort)(__float_as_uint(lof) >> 16);
}

// ---------------- MFMA edge transform + LDS aggregation ----------------
// One block per 64-dst tile; wave w handles combos w, w+4, w+8, w+12.
// Per 32-edge group: D[64 feat][32 edge] = M_c * H_src via 24 MFMA (3-term split),
// then predicated LDS float atomics into acc[dl*65 + feat].
__global__ __launch_bounds__(256, 3)
void k_msgM(const ushort* __restrict__ hhi, const ushort* __restrict__ hlo,
            const float* __restrict__ hres, const int* __restrict__ elist,
            const int* __restrict__ seg, const ushort* __restrict__ Ahi,
            const ushort* __restrict__ Alo, float* __restrict__ outb,
            float* __restrict__ pbuf)
{
    __shared__ float acc[TILE_N * 65];
    __shared__ float rsum[4][64], rsq[4][64];
    const int tid = threadIdx.x;
    const int w = tid >> 6, lane = tid & 63;
    const int col = lane & 31, hi = lane >> 5;
    const int tile = blockIdx.x;

    for (int i = tid; i < TILE_N * 65; i += 256) acc[i] = 0.f;
    __syncthreads();

    for (int ci = 0; ci < 4; ++ci) {
        const int c = w + 4 * ci;
        // A fragments for this combo (register-resident across the edge loop)
        short8 ahi[2][4], alo[2][4];
#pragma unroll
        for (int t = 0; t < 2; ++t)
#pragma unroll
            for (int s = 0; s < 4; ++s) {
                const int fid = ((c * 2 + t) * 4 + s) * 64 + lane;
                ahi[t][s] = *(const short8*)&Ahi[fid * 8];
                alo[t][s] = *(const short8*)&Alo[fid * 8];
            }
        const int s0 = seg[tile * 16 + c];
        const int s1 = seg[tile * 16 + c + 1];

        for (int p = s0; p < s1; p += 32) {
            const int idx = p + col;
            const int ep = (idx < s1) ? elist[idx] : (255 << 16);
            const int srcn = ep & 0xFFFF;
            const int dl = ep >> 16;

            // B fragments: 8 bf16 of h[src] at k = 16s + 8*hi + j
            const ushort* __restrict__ rh = hhi + srcn * 64 + hi * 8;
            const ushort* __restrict__ rl = hlo + srcn * 64 + hi * 8;
            short8 bhi[4], blo[4];
#pragma unroll
            for (int s = 0; s < 4; ++s) {
                bhi[s] = *(const short8*)&rh[s * 16];
                blo[s] = *(const short8*)&rl[s * 16];
            }

            f32x16 c0 = {0.f}, c1 = {0.f};
#pragma unroll
            for (int i = 0; i < 16; ++i) { c0[i] = 0.f; c1[i] = 0.f; }
#pragma unroll
            for (int s = 0; s < 4; ++s) {
                c0 = __builtin_amdgcn_mfma_f32_32x32x16_bf16(ahi[0][s], bhi[s], c0, 0, 0, 0);
                c1 = __builtin_amdgcn_mfma_f32_32x32x16_bf16(ahi[1][s], bhi[s], c1, 0, 0, 0);
                c0 = __builtin_amdgcn_mfma_f32_32x32x16_bf16(ahi[0][s], blo[s], c0, 0, 0, 0);
                c1 = __builtin_amdgcn_mfma_f32_32x32x16_bf16(ahi[1][s], blo[s], c1, 0, 0, 0);
                c0 = __builtin_amdgcn_mfma_f32_32x32x16_bf16(alo[0][s], bhi[s], c0, 0, 0, 0);
                c1 = __builtin_amdgcn_mfma_f32_32x32x16_bf16(alo[1][s], bhi[s], c1, 0, 0, 0);
            }

            if (dl < 64) {
                const int base = dl * 65 + 4 * hi;
#pragma unroll
                for (int r = 0; r < 16; ++r) {
                    const int fp = (r & 3) + 8 * (r >> 2);
                    atomicAdd(&acc[base + fp], c0[r]);
                    atomicAdd(&acc[base + fp + 32], c1[r]);
                }
            }
        }
    }
    __syncthreads();

    // epilogue: residual + store + LN partials
    const int o = lane;
    float s1v = 0.f, s2v = 0.f;
#pragma unroll
    for (int i = 0; i < 16; ++i) {
        const int d = w * 16 + i;
        const int gd = tile * TILE_N + d;
        if (gd < N_NODESC) {
            const float v = acc[d * 65 + o] + hres[(long)gd * 64 + o];
            outb[(long)gd * 64 + o] = v;
            s1v += v; s2v += v * v;
        }
    }
    rsum[w][o] = s1v; rsq[w][o] = s2v;
    __syncthreads();
    if (tid < 64) {
        float t1 = 0.f, t2 = 0.f;
#pragma unroll
        for (int k = 0; k < 4; ++k) { t1 += rsum[k][tid]; t2 += rsq[k][tid]; }
        pbuf[tile * 128 + tid] = t1;
        pbuf[tile * 128 + 64 + tid] = t2;
    }
}

// ---------------- reduce LN partials -> scale/shift ----------------
__global__ __launch_bounds__(1024)
void k_norm2(const float* __restrict__ pbuf, const float* __restrict__ g,
             const float* __restrict__ be, float* __restrict__ scale,
             float* __restrict__ shift)
{
    __shared__ float s[1024];
    const int t = threadIdx.x, j = t & 127, gg = t >> 7;
    float a = 0.f;
    for (int b = gg; b < NTILE2; b += 8) a += pbuf[b * 128 + j];
    s[t] = a;
    __syncthreads();
    if (t < 128) {
        float tot = 0.f;
#pragma unroll
        for (int k = 0; k < 8; ++k) tot += s[j + 128 * k];
        s[t] = tot;
    }
    __syncthreads();
    if (t < 64) {
        const double mu  = (double)s[t] / (double)N_NODESC;
        const double var = (double)s[64 + t] / (double)N_NODESC - mu * mu;
        const double sc  = (double)g[t] / sqrt(var + (double)EPSF);
        scale[t] = (float)sc;
        shift[t] = (float)((double)be[t] - mu * sc);
    }
}

// ---------------- final projection (LN apply fused) ----------------
__global__ __launch_bounds__(256)
void k_out(const float* __restrict__ outb, const float* __restrict__ scale,
           const float* __restrict__ shift, const float* __restrict__ resW,
           const float* __restrict__ resb, float* __restrict__ out)
{
    const int n = blockIdx.x * 256 + threadIdx.x;
    if (n >= N_NODESC) return;
    float a0 = resb[0], a1 = resb[1];
    const float* __restrict__ r = outb + (long)n * 64;
#pragma unroll 8
    for (int e = 0; e < 64; ++e) {
        const float v = fmaxf(r[e] * scale[e] + shift[e], 0.f);
        a0 += v * resW[2 * e];
        a1 += v * resW[2 * e + 1];
    }
    out[2 * n] = a0;
    out[2 * n + 1] = a1;
}

extern "C" void kernel_launch(void* const* d_in, const int* in_sizes, int n_in,
                              void* d_out, int out_size, void* d_ws, size_t ws_size,
                              hipStream_t stream)
{
    const float* x      = (const float*)d_in[0];
    const float* M      = (const float*)d_in[1];
    const int*   src    = (const int*)d_in[2];
    const int*   dst    = (const int*)d_in[3];
    const int*   labels = (const int*)d_in[4];
    const int*   bidx   = (const int*)d_in[5];
    const float* resW   = (const float*)d_in[18];
    const float* resb   = (const float*)d_in[19];
    float* out = (float*)d_out;

    char* ws = (char*)d_ws;
    float*  scale = (float*)(ws + WS_SCALE);
    float*  shift = (float*)(ws + WS_SHIFT);
    int*    bsum  = (int*)(ws + WS_BSUM);
    float*  pbuf  = (float*)(ws + WS_PBUF);
    int*    hist  = (int*)(ws + WS_HIST);
    int*    fill  = (int*)(ws + WS_FILL);
    int*    seg   = (int*)(ws + WS_SEG);
    int*    elist = (int*)(ws + WS_ELIST);
    ushort* Ahi   = (ushort*)(ws + WS_AHI);
    ushort* Alo   = (ushort*)(ws + WS_ALO);
    ushort* hhi   = (ushort*)(ws + WS_HHI);
    ushort* hlo   = (ushort*)(ws + WS_HLO);
    float*  hB    = (float*)(ws + WS_HB);
    float*  outb  = (float*)(ws + WS_OUTB);

    const int NB64 = (N_NODESC * 64 + 255) / 256;  // 12500

    // ---- preprocessing (graph + M constant across layers) ----
    hipMemsetAsync(hist, 0, 2 * NKPAD * sizeof(int), stream);   // hist + fill
    k_hist<<<NEBLK, 256, 0, stream>>>(src, dst, labels, bidx, hist);
    k_bsum<<<NKBLK, 256, 0, stream>>>(hist, bsum);
    k_bscan<<<1, 64, 0, stream>>>(bsum);
    k_escan<<<NKBLK, 256, 0, stream>>>(hist, bsum, seg);
    k_scat<<<NEBLK, 256, 0, stream>>>(src, dst, labels, bidx, seg, fill, elist);
    k_mfrag<<<16, 256, 0, stream>>>(M, Ahi, Alo);

    for (int l = 0; l < 3; ++l) {
        const float* W  = (const float*)d_in[6 + 4 * l];
        const float* b  = (const float*)d_in[7 + 4 * l];
        const float* g  = (const float*)d_in[8 + 4 * l];
        const float* be = (const float*)d_in[9 + 4 * l];

        if (l == 0) {
            k_h<<<NB64, 256, 0, stream>>>(x, W, b, hB, hhi, hlo, 128);
        } else {
            k_happly<<<N_NODESC / 4, 256, 0, stream>>>(outb, scale, shift, W, b,
                                                       hB, hhi, hlo);
        }
        k_msgM<<<NTILE2, 256, 0, stream>>>(hhi, hlo, hB, elist, seg, Ahi, Alo,
                                           outb, pbuf);
        k_norm2<<<1, 1024, 0, stream>>>(pbuf, g, be, scale, shift);
    }
    k_out<<<(N_NODESC + 255) / 256, 256, 0, stream>>>(outb, scale, shift, resW, resb, out);
    (void)in_sizes; (void)n_in; (void)out_size; (void)ws_size;
}